// Round 1
// baseline (462.472 us; speedup 1.0000x reference)
//
#include <hip/hip_runtime.h>

typedef float        f32x4  __attribute__((ext_vector_type(4)));
typedef __bf16       bf16x8 __attribute__((ext_vector_type(8)));
typedef unsigned int u32x4  __attribute__((ext_vector_type(4)));

#define NN   8192
#define IND  256
#define OUTD 128
#define NB   144   // 9 n-tiles of 16: cols 0..127 = w*Wh, col 128 = w (denominator), 129..143 = 0

__device__ __forceinline__ bf16x8 cvt2(f32x4 a, f32x4 b) {
  bf16x8 r;
  r[0]=(__bf16)a[0]; r[1]=(__bf16)a[1]; r[2]=(__bf16)a[2]; r[3]=(__bf16)a[3];
  r[4]=(__bf16)b[0]; r[5]=(__bf16)b[1]; r[6]=(__bf16)b[2]; r[7]=(__bf16)b[3];
  return r;
}

// K1: Wh = X @ W^T   [8192,128] fp32 (stored raw), e[j] = relu(Wh[j]) . a_w
// wave = 16 rows; A-frag: lane reads X[row=base+(lane&15)][k=quad*8..+8]
// B-frag: B[k][n] = W[n][k] -> lane reads W[n0+(lane&15)][k..k+8] (contiguous)
__global__ __launch_bounds__(128) void k1_wh_e(const float* __restrict__ X,
                                               const float* __restrict__ W,
                                               const float* __restrict__ aw,
                                               float* __restrict__ Wh,
                                               float* __restrict__ ev) {
  const int lane = threadIdx.x & 63;
  const int wave = threadIdx.x >> 6;
  const int nlo  = lane & 15;
  const int quad = lane >> 4;
  const int rowBase = blockIdx.x * 32 + wave * 16;

  const float* xp = X + (size_t)(rowBase + nlo) * IND + quad * 8;
  f32x4 acc[8];
#pragma unroll
  for (int nt = 0; nt < 8; ++nt) acc[nt] = f32x4{0.f, 0.f, 0.f, 0.f};

#pragma unroll
  for (int kb = 0; kb < IND; kb += 32) {
    f32x4 a0 = *(const f32x4*)(xp + kb);
    f32x4 a1 = *(const f32x4*)(xp + kb + 4);
    bf16x8 af = cvt2(a0, a1);
#pragma unroll
    for (int nt = 0; nt < 8; ++nt) {
      const float* wp = W + (size_t)(nt * 16 + nlo) * IND + kb + quad * 8;
      f32x4 b0 = *(const f32x4*)wp;
      f32x4 b1 = *(const f32x4*)(wp + 4);
      acc[nt] = __builtin_amdgcn_mfma_f32_16x16x32_bf16(af, cvt2(b0, b1), acc[nt], 0, 0, 0);
    }
  }
  // C layout: col = nt*16 + (lane&15), row = quad*4 + reg
  float p0 = 0.f, p1 = 0.f, p2 = 0.f, p3 = 0.f;
#pragma unroll
  for (int nt = 0; nt < 8; ++nt) {
    const int col = nt * 16 + nlo;
    const float awc = aw[col];
    const int r0 = rowBase + quad * 4;
    float v0 = acc[nt][0], v1 = acc[nt][1], v2 = acc[nt][2], v3 = acc[nt][3];
    Wh[(size_t)(r0 + 0) * OUTD + col] = v0;
    Wh[(size_t)(r0 + 1) * OUTD + col] = v1;
    Wh[(size_t)(r0 + 2) * OUTD + col] = v2;
    Wh[(size_t)(r0 + 3) * OUTD + col] = v3;
    p0 += fmaxf(v0, 0.f) * awc;
    p1 += fmaxf(v1, 0.f) * awc;
    p2 += fmaxf(v2, 0.f) * awc;
    p3 += fmaxf(v3, 0.f) * awc;
  }
#pragma unroll
  for (int off = 8; off; off >>= 1) {  // reduce across the 16 lanes sharing a quad
    p0 += __shfl_xor(p0, off, 64);
    p1 += __shfl_xor(p1, off, 64);
    p2 += __shfl_xor(p2, off, 64);
    p3 += __shfl_xor(p3, off, 64);
  }
  if (nlo == 0) {
    const int r0 = rowBase + quad * 4;
    ev[r0 + 0] = p0; ev[r0 + 1] = p1; ev[r0 + 2] = p2; ev[r0 + 3] = p3;
  }
}

// K2: build B^T [NB][NN] bf16: row n<128: w_j*Wh[j][n]; row 128: w_j; rows 129..143: 0
__global__ __launch_bounds__(256) void k2_bt(const float* __restrict__ Wh,
                                             const float* __restrict__ ev,
                                             __bf16* __restrict__ Bt) {
  const int j = blockIdx.x * 256 + threadIdx.x;
  const float w = expf(ev[j]);
  const int n0 = blockIdx.y * 18;  // 8 * 18 = 144
#pragma unroll
  for (int i = 0; i < 18; ++i) {
    const int n = n0 + i;
    float v = 0.f;
    if (n < OUTD) v = w * Wh[(size_t)j * OUTD + n];
    else if (n == OUTD) v = w;
    Bt[(size_t)n * NN + j] = (__bf16)v;
  }
}

// K3: C[8192 x 144] = Adj(fp32->bf16) @ B ; epilogue relu(num/den)
// 256 WGs x 4 waves; WG = 32 rows, K split 4x2048 across waves; LDS cross-wave reduce.
__global__ __launch_bounds__(256, 1) void k3_gemm(const float* __restrict__ Adj,
                                                  const __bf16* __restrict__ Bt,
                                                  float* __restrict__ out) {
  __shared__ float red[3][32][145];  // 55.7 KB; +1 pad breaks bank aliasing
  const int lane = threadIdx.x & 63;
  const int wave = threadIdx.x >> 6;
  const int nlo  = lane & 15;
  const int quad = lane >> 4;
  const int rowBase = blockIdx.x * 32;
  const int k0 = wave * 2048;

  f32x4 acc[2][9];
#pragma unroll
  for (int mm = 0; mm < 2; ++mm)
#pragma unroll
    for (int nt = 0; nt < 9; ++nt) acc[mm][nt] = f32x4{0.f, 0.f, 0.f, 0.f};

  const float*  ap0 = Adj + (size_t)(rowBase + nlo) * NN + quad * 8 + k0;
  const float*  ap1 = ap0 + (size_t)16 * NN;
  const __bf16* bp  = Bt + (size_t)nlo * NN + quad * 8 + k0;

  for (int kb = 0; kb < 2048; kb += 32) {
    // A fragments: streamed once -> nontemporal (evict-first, protect Bt in L2)
    f32x4 x0 = __builtin_nontemporal_load((const f32x4*)(ap0 + kb));
    f32x4 x1 = __builtin_nontemporal_load((const f32x4*)(ap0 + kb + 4));
    f32x4 y0 = __builtin_nontemporal_load((const f32x4*)(ap1 + kb));
    f32x4 y1 = __builtin_nontemporal_load((const f32x4*)(ap1 + kb + 4));
    u32x4 braw[9];
#pragma unroll
    for (int nt = 0; nt < 9; ++nt)
      braw[nt] = *(const u32x4*)(bp + (size_t)nt * 16 * NN + kb);
    bf16x8 af0 = cvt2(x0, x1);
    bf16x8 af1 = cvt2(y0, y1);
#pragma unroll
    for (int nt = 0; nt < 9; ++nt) {
      bf16x8 bfv = __builtin_bit_cast(bf16x8, braw[nt]);
      acc[0][nt] = __builtin_amdgcn_mfma_f32_16x16x32_bf16(af0, bfv, acc[0][nt], 0, 0, 0);
      acc[1][nt] = __builtin_amdgcn_mfma_f32_16x16x32_bf16(af1, bfv, acc[1][nt], 0, 0, 0);
    }
  }

  if (wave) {
    float (*slot)[145] = red[wave - 1];
#pragma unroll
    for (int mm = 0; mm < 2; ++mm)
#pragma unroll
      for (int nt = 0; nt < 9; ++nt)
#pragma unroll
        for (int rg = 0; rg < 4; ++rg)
          slot[mm * 16 + quad * 4 + rg][nt * 16 + nlo] = acc[mm][nt][rg];
  }
  __syncthreads();
  if (wave == 0) {
#pragma unroll
    for (int mm = 0; mm < 2; ++mm) {
#pragma unroll
      for (int nt = 0; nt < 9; ++nt)
#pragma unroll
        for (int rg = 0; rg < 4; ++rg) {
          const int r = mm * 16 + quad * 4 + rg;
          const int c = nt * 16 + nlo;
          acc[mm][nt][rg] += red[0][r][c] + red[1][r][c] + red[2][r][c];
        }
      float inv[4];
#pragma unroll
      for (int rg = 0; rg < 4; ++rg)  // den lives at col 128 = (nt=8, lane&15==0)
        inv[rg] = 1.0f / __shfl(acc[mm][8][rg], quad << 4, 64);
#pragma unroll
      for (int nt = 0; nt < 8; ++nt)
#pragma unroll
        for (int rg = 0; rg < 4; ++rg) {
          const int row = rowBase + mm * 16 + quad * 4 + rg;
          out[(size_t)row * OUTD + nt * 16 + nlo] = fmaxf(acc[mm][nt][rg] * inv[rg], 0.f);
        }
    }
  }
}

extern "C" void kernel_launch(void* const* d_in, const int* in_sizes, int n_in,
                              void* d_out, int out_size, void* d_ws, size_t ws_size,
                              hipStream_t stream) {
  const float* X  = (const float*)d_in[0];
  const float* A  = (const float*)d_in[1];
  const float* W  = (const float*)d_in[2];
  const float* aw = (const float*)d_in[3];
  float* out = (float*)d_out;

  char* ws = (char*)d_ws;
  float*  Wh = (float*)ws;                     // 8192*128*4  = 4 MiB
  float*  ev = (float*)(ws + 4194304);         // 8192*4      = 32 KiB
  __bf16* Bt = (__bf16*)(ws + 4227072);        // 144*8192*2  = 2.25 MiB

  k1_wh_e<<<256, 128, 0, stream>>>(X, W, aw, Wh, ev);
  k2_bt<<<dim3(32, 8), 256, 0, stream>>>(Wh, ev, Bt);
  k3_gemm<<<256, 256, 0, stream>>>(A, Bt, out);
}